// Round 6
// baseline (241.616 us; speedup 1.0000x reference)
//
#include <hip/hip_runtime.h>
#include <math.h>

#define B_   4
#define N_   2048
#define DIM_ 512
#define T_   16
#define H_   8
#define DH_  64
// num_patches = 128; 64-token tiles align within patches -> decay scalar per tile pair

typedef unsigned short ushort_t;
typedef __attribute__((ext_vector_type(8))) short bf16x8;    // 8 bf16 = 4 VGPRs
typedef __attribute__((ext_vector_type(16))) float f32x16;   // 32x32 MFMA acc

__device__ inline ushort_t bf16_rn(float x) {
  unsigned u = __builtin_bit_cast(unsigned, x);
  u += 0x7FFFu + ((u >> 16) & 1u);
  return (ushort_t)(u >> 16);
}
__device__ inline float bf16f(ushort_t h) {
  return __builtin_bit_cast(float, (unsigned)h << 16);
}
__device__ inline unsigned pack2(ushort_t a, ushort_t b) {
  return (unsigned)a | ((unsigned)b << 16);
}
__device__ inline void split2(float x, ushort_t &h, ushort_t &l) {
  h = bf16_rn(x);
  l = bf16_rn(x - bf16f(h));
}
// v_cvt_pk_bf16_f32: D = {lo: bf16(lo), hi: bf16(hi)}, RNE (same bits as bf16_rn)
__device__ inline unsigned cvt_pk_bf16(float lo, float hi) {
  unsigned r;
  asm("v_cvt_pk_bf16_f32 %0, %1, %2" : "=v"(r) : "v"(lo), "v"(hi));
  return r;
}
// v_permlane32_swap_b32: x.hi32lanes <-> y.lo32lanes
__device__ inline void permlane32_swap(unsigned &x, unsigned &y) {
  asm volatile("v_permlane32_swap_b32 %0, %1" : "+v"(x), "+v"(y));
}
// raw v_exp_f32 (2^x): args here are >=0 and normal-range -> identical result
// to exp2f without OCML's wrapper instructions
__device__ inline float exp2_raw(float x) {
  float r;
  asm("v_exp_f32 %0, %1" : "=v"(r) : "v"(x));
  return r;
}
// async global->LDS, 16B per lane; LDS dest = wave-uniform base + lane*16
__device__ inline void gload_lds16(const ushort_t* g, ushort_t* l) {
  __builtin_amdgcn_global_load_lds(
      (const __attribute__((address_space(1))) unsigned int*)(g),
      (__attribute__((address_space(3))) unsigned int*)(l),
      16, 0, 0);
}

// ---------------------------------------------------------------------------
// Kernel A: merged prep. Blocks 0..191: Wqkv transpose+split; 192..255: Wout;
// 256..2303: LayerNorm -> xn hi/lo.
// ---------------------------------------------------------------------------
__global__ __launch_bounds__(256) void prep_kernel(
    const float* __restrict__ x, const float* __restrict__ gamma,
    const float* __restrict__ beta, const float* __restrict__ Wqkv,
    const float* __restrict__ Wout,
    ushort_t* __restrict__ xnh, ushort_t* __restrict__ xnl,
    ushort_t* __restrict__ wqh, ushort_t* __restrict__ wql,
    ushort_t* __restrict__ woh, ushort_t* __restrict__ wol) {
  __shared__ float Ts[64][68];
  int bidx = blockIdx.x;
  int tid = threadIdx.x;
  if (bidx < 256) {
    const float* src; ushort_t* dh; ushort_t* dl; int Nn, n0, k0;
    if (bidx < 192) {
      src = Wqkv; dh = wqh; dl = wql; Nn = 1536;
      n0 = (bidx % 24) * 64; k0 = (bidx / 24) * 64;
    } else {
      int l = bidx - 192;
      src = Wout; dh = woh; dl = wol; Nn = 512;
      n0 = (l % 8) * 64; k0 = (l / 8) * 64;
    }
#pragma unroll
    for (int it = 0; it < 4; ++it) {
      int idx = tid + it * 256;
      int r = idx >> 4, c4 = (idx & 15) * 4;
      *(float4*)&Ts[r][c4] = *(const float4*)&src[(size_t)(k0 + r) * Nn + n0 + c4];
    }
    __syncthreads();
#pragma unroll
    for (int it = 0; it < 2; ++it) {
      int idx = tid + it * 256;
      int n = idx >> 3, kc = (idx & 7) * 8;
      ushort_t hs[8], ls[8];
#pragma unroll
      for (int j = 0; j < 8; ++j) split2(Ts[kc + j][n], hs[j], ls[j]);
      uint4 uh, ul;
      uh.x = pack2(hs[0], hs[1]); uh.y = pack2(hs[2], hs[3]);
      uh.z = pack2(hs[4], hs[5]); uh.w = pack2(hs[6], hs[7]);
      ul.x = pack2(ls[0], ls[1]); ul.y = pack2(ls[2], ls[3]);
      ul.z = pack2(ls[4], ls[5]); ul.w = pack2(ls[6], ls[7]);
      size_t o = (size_t)(n0 + n) * 512 + k0 + kc;
      *(uint4*)&dh[o] = uh;
      *(uint4*)&dl[o] = ul;
    }
  } else {
    int row  = (bidx - 256) * 4 + (tid >> 6);
    int lane = tid & 63;
    const float4* xr = (const float4*)(x + (size_t)row * DIM_);
    float4 v0 = xr[lane * 2 + 0];
    float4 v1 = xr[lane * 2 + 1];
    float s  = v0.x + v0.y + v0.z + v0.w + v1.x + v1.y + v1.z + v1.w;
    float ss = v0.x*v0.x + v0.y*v0.y + v0.z*v0.z + v0.w*v0.w
             + v1.x*v1.x + v1.y*v1.y + v1.z*v1.z + v1.w*v1.w;
#pragma unroll
    for (int off = 32; off > 0; off >>= 1) {
      s  += __shfl_xor(s, off);
      ss += __shfl_xor(ss, off);
    }
    float mu  = s * (1.0f / DIM_);
    float var = ss * (1.0f / DIM_) - mu * mu;
    float rstd = rsqrtf(var + 1e-5f);
    float4 g0 = *(const float4*)&gamma[lane * 8];
    float4 g1 = *(const float4*)&gamma[lane * 8 + 4];
    float4 b0 = *(const float4*)&beta[lane * 8];
    float4 b1 = *(const float4*)&beta[lane * 8 + 4];
    float xv[8] = {v0.x, v0.y, v0.z, v0.w, v1.x, v1.y, v1.z, v1.w};
    float gv[8] = {g0.x, g0.y, g0.z, g0.w, g1.x, g1.y, g1.z, g1.w};
    float bv[8] = {b0.x, b0.y, b0.z, b0.w, b1.x, b1.y, b1.z, b1.w};
    ushort_t hs[8], ls[8];
#pragma unroll
    for (int j = 0; j < 8; ++j) {
      float xn = (xv[j] - mu) * rstd * gv[j] + bv[j];
      split2(xn, hs[j], ls[j]);
    }
    uint4 uh, ul;
    uh.x = pack2(hs[0], hs[1]); uh.y = pack2(hs[2], hs[3]);
    uh.z = pack2(hs[4], hs[5]); uh.w = pack2(hs[6], hs[7]);
    ul.x = pack2(ls[0], ls[1]); ul.y = pack2(ls[2], ls[3]);
    ul.z = pack2(ls[4], ls[5]); ul.w = pack2(ls[6], ls[7]);
    size_t o = (size_t)row * DIM_ + lane * 8;
    *(uint4*)&xnh[o] = uh;
    *(uint4*)&xnl[o] = ul;
  }
}

// ---------------------------------------------------------------------------
// Kernel C: qkv = xn @ Wqkv^T (R8-proven body + XCD-aware 1D decode). Exact
// R1 form (no prefetch, no setprio).
// ---------------------------------------------------------------------------
__global__ __launch_bounds__(256) void qkv_gemm_mfma(
    const ushort_t* __restrict__ xnh, const ushort_t* __restrict__ xnl,
    const ushort_t* __restrict__ wth, const ushort_t* __restrict__ wtl,
    ushort_t* __restrict__ qh, ushort_t* __restrict__ ql,
    ushort_t* __restrict__ kho, ushort_t* __restrict__ klo,
    ushort_t* __restrict__ vt) {
  __shared__ ushort_t Ah[128 * 40], Al[128 * 40], Bh[128 * 40], Bl[128 * 40];
  int tid = threadIdx.x;
  int w = tid >> 6, lane = tid & 63, l31 = lane & 31, g = lane >> 5;
  int wm = w >> 1, wn = w & 1;
  int idx = blockIdx.x;
  int xcd = idx & 7, local = idx >> 3;
  int n0 = (local % 12) * 128;
  int m0 = ((local / 12) * 8 + xcd) * 128;

  f32x16 acc[2][2];
#pragma unroll
  for (int i = 0; i < 2; ++i)
#pragma unroll
    for (int j = 0; j < 2; ++j)
#pragma unroll
      for (int e = 0; e < 16; ++e) acc[i][j][e] = 0.0f;

  int fm[2], fc[2];
#pragma unroll
  for (int it = 0; it < 2; ++it) {
    int f = tid + it * 256;
    fm[it] = f >> 2;
    fc[it] = (f & 3) * 8;
  }

#pragma unroll 1
  for (int kt = 0; kt < 16; ++kt) {
    __syncthreads();
#pragma unroll
    for (int it = 0; it < 2; ++it) {
      size_t ao = (size_t)(m0 + fm[it]) * 512 + kt * 32 + fc[it];
      size_t bo = (size_t)(n0 + fm[it]) * 512 + kt * 32 + fc[it];
      uint4 tah = *(const uint4*)&xnh[ao];
      uint4 tal = *(const uint4*)&xnl[ao];
      uint4 tbh = *(const uint4*)&wth[bo];
      uint4 tbl = *(const uint4*)&wtl[bo];
      int o = fm[it] * 40 + fc[it];
      *(uint4*)&Ah[o] = tah;
      *(uint4*)&Al[o] = tal;
      *(uint4*)&Bh[o] = tbh;
      *(uint4*)&Bl[o] = tbl;
    }
    __syncthreads();
#pragma unroll
    for (int kc = 0; kc < 2; ++kc) {
      int off = kc * 16 + 8 * g;
      bf16x8 afh[2], afl[2], bfh[2], bfl[2];
#pragma unroll
      for (int rb = 0; rb < 2; ++rb) {
        int r = (wm * 64 + rb * 32 + l31) * 40 + off;
        afh[rb] = *(const bf16x8*)&Ah[r];
        afl[rb] = *(const bf16x8*)&Al[r];
      }
#pragma unroll
      for (int cb = 0; cb < 2; ++cb) {
        int r = (wn * 64 + cb * 32 + l31) * 40 + off;
        bfh[cb] = *(const bf16x8*)&Bh[r];
        bfl[cb] = *(const bf16x8*)&Bl[r];
      }
#pragma unroll
      for (int rb = 0; rb < 2; ++rb)
#pragma unroll
        for (int cb = 0; cb < 2; ++cb) {
          acc[rb][cb] = __builtin_amdgcn_mfma_f32_32x32x16_bf16(afh[rb], bfh[cb], acc[rb][cb], 0, 0, 0);
          acc[rb][cb] = __builtin_amdgcn_mfma_f32_32x32x16_bf16(afh[rb], bfl[cb], acc[rb][cb], 0, 0, 0);
          acc[rb][cb] = __builtin_amdgcn_mfma_f32_32x32x16_bf16(afl[rb], bfh[cb], acc[rb][cb], 0, 0, 0);
        }
    }
  }

  int part = n0 >> 9;
#pragma unroll
  for (int rb = 0; rb < 2; ++rb) {
    int m_base = m0 + wm * 64 + rb * 32;
#pragma unroll
    for (int cb = 0; cb < 2; ++cb) {
      int n_g = n0 + wn * 64 + cb * 32 + l31;
      int rem = n_g & 511, hh = rem >> 6, d = rem & 63;
      if (part == 2) {
#pragma unroll
        for (int grp = 0; grp < 4; ++grp) {
          int m_g = m_base + grp * 8 + 4 * g;
          int bb = m_g >> 11, tok = m_g & 2047;
          uint2 pk;
          pk.x = pack2(bf16_rn(acc[rb][cb][grp * 4 + 0]), bf16_rn(acc[rb][cb][grp * 4 + 1]));
          pk.y = pack2(bf16_rn(acc[rb][cb][grp * 4 + 2]), bf16_rn(acc[rb][cb][grp * 4 + 3]));
          *(uint2*)&vt[((size_t)(bb * 8 + hh) * 64 + d) * 2048 + tok] = pk;
        }
      } else {
        float sc = (part == 0) ? 0.125f : 1.0f;
        ushort_t* dsth = (part == 0) ? qh : kho;
        ushort_t* dstl = (part == 0) ? ql : klo;
#pragma unroll
        for (int reg = 0; reg < 16; ++reg) {
          int row = (reg & 3) + 8 * (reg >> 2) + 4 * g;
          int m_g = m_base + row;
          int bb = m_g >> 11, tok = m_g & 2047;
          ushort_t hi, lo;
          split2(acc[rb][cb][reg] * sc, hi, lo);
          size_t addr = ((size_t)(bb * 8 + hh) * 2048 + tok) * 64 + d;
          dsth[addr] = hi;
          dstl[addr] = lo;
        }
      }
    }
  }
}

// ---------------------------------------------------------------------------
// Kernel D: MFMA attention. 64 q / 2-wave blocks, grid (32,32)=1024 ->
// 4 independent barrier groups per CU (was 2): phase stalls of one block
// hide under compute of the other three. Single-buffered K/V LDS (27.7 KB)
// with a watertight 2-barrier schedule (also fixes R5's latent race):
//   [auto vmcnt for own loads] ds_read all 24 frags -> regs
//   s_waitcnt lgkmcnt(0); B1        <- reads done, buffer free
//   stage kt+1 into SAME buffer (13-14 gloads/wave, chunk trick for [64][72])
//   register-only compute (QK^T swapped softmax T12, PV) with T5 setprio
//   s_waitcnt vmcnt(0) (free: issued a compute-phase ago); B2
//   -> after B2 ALL waves' loads landed => next ds_reads safe.
// exp via raw v_exp_f32 (args >=0, normal range == exp2f result bits).
// ---------------------------------------------------------------------------
__global__ __launch_bounds__(128, 2) void attn_mfma(
    const ushort_t* __restrict__ qh, const ushort_t* __restrict__ ql,
    const ushort_t* __restrict__ kho, const ushort_t* __restrict__ klo,
    const ushort_t* __restrict__ vt, const float* __restrict__ R,
    const float* __restrict__ a, const float* __restrict__ c,
    ushort_t* __restrict__ aoh, ushort_t* __restrict__ aol) {
  __shared__ __align__(16) ushort_t KhS[4608];
  __shared__ __align__(16) ushort_t KlS[4608];
  __shared__ __align__(16) ushort_t VtS[4608];
  __shared__ float rsS[64];
  __shared__ float decl2S[16];

  int tid = threadIdx.x;
  int w = tid >> 6, lane = tid & 63, l31 = lane & 31, g = lane >> 5;
  int bh = blockIdx.x;
  int qt = blockIdx.y;               // 64-query tile; timepoint = qt>>1
  int b = bh >> 3, h = bh & 7;

  // Q fragments: wave w owns rows qt*64 + w*32 .. +32 (q = l31 -> B operand col)
  int qrow = qt * 64 + w * 32 + l31;
  size_t qoff = ((size_t)bh * 2048 + qrow) * 64;
  bf16x8 qfh[4], qfl[4];
#pragma unroll
  for (int d0i = 0; d0i < 4; ++d0i) {
    qfh[d0i] = *(const bf16x8*)&qh[qoff + d0i * 16 + 8 * g];
    qfl[d0i] = *(const bf16x8*)&ql[qoff + d0i * 16 + 8 * g];
  }

  const ushort_t* kbase = kho + (size_t)bh * 2048 * 64;
  const ushort_t* lbase = klo + (size_t)bh * 2048 * 64;
  const ushort_t* vbase = vt + (size_t)bh * 64 * 2048;

  // decay table: 16 kt-pairs, log2e folded in
  if (tid < 16) {
    float aab = fabsf(a[h]);
    float cab = fabsf(c[h]);
    float Rv = R[b * (T_ * T_) + (qt >> 1) * T_ + tid];
    decl2S[tid] = 1.4426950408889634f / (1.0f + __expf(aab * Rv - cab));
  }

  // padded-stride staging map ([64][72], 144B row = 9 x 16B slots):
  // chunk c, lane l covers ushort idx u = c*512 + l*8 -> row u/72, slot
  // (u%72)/8; slot 8 = pad (fetch harmless duplicate). Wave w stages chunks
  // {4w..4w+3} of each array + chunk 8 of Kh,Kl (w0) / Vt (w1).
  int r_[4], j8_[4];
#pragma unroll
  for (int i = 0; i < 4; ++i) {
    int u = (w * 4 + i) * 512 + lane * 8;
    int r = u / 72;
    int j = (u - r * 72) >> 3;
    r_[i] = r;
    j8_[i] = (j == 8) ? 0 : (j << 3);
  }
  int u8 = 8 * 512 + lane * 8;
  int r8 = u8 / 72;
  int j8v = (u8 - r8 * 72) >> 3;
  int j88 = (j8v == 8) ? 0 : (j8v << 3);

  f32x16 oacc[2];
#pragma unroll
  for (int t = 0; t < 2; ++t)
#pragma unroll
    for (int i = 0; i < 16; ++i) oacc[t][i] = 0.0f;
  float rsp[4] = {0.0f, 0.0f, 0.0f, 0.0f};

  // prologue: stage kt=0; __syncthreads = vmcnt0+lgkm0+barrier (full drain)
  {
#pragma unroll
    for (int i = 0; i < 4; ++i) {
      int cb = (w * 4 + i) * 512;
      gload_lds16(&kbase[(size_t)r_[i] * 64 + j8_[i]], &KhS[cb]);
      gload_lds16(&lbase[(size_t)r_[i] * 64 + j8_[i]], &KlS[cb]);
      gload_lds16(&vbase[(size_t)r_[i] * 2048 + j8_[i]], &VtS[cb]);
    }
    if (w == 0) {
      gload_lds16(&kbase[(size_t)r8 * 64 + j88], &KhS[8 * 512]);
      gload_lds16(&lbase[(size_t)r8 * 64 + j88], &KlS[8 * 512]);
    } else {
      gload_lds16(&vbase[(size_t)r8 * 2048 + j88], &VtS[8 * 512]);
    }
  }
  __syncthreads();

#pragma unroll 1
  for (int kt = 0; kt < 32; ++kt) {
    // --- Phase 1: ds_read ALL fragments of the tile into registers
    float decl2 = decl2S[kt >> 1];
    bf16x8 kfh[2][4], kfl[2][4], vf[2][4];
#pragma unroll
    for (int khalf = 0; khalf < 2; ++khalf) {
      int krow = (khalf * 32 + l31) * 72;
#pragma unroll
      for (int d0i = 0; d0i < 4; ++d0i) {
        int off = krow + d0i * 16 + 8 * g;
        kfh[khalf][d0i] = *(const bf16x8*)&KhS[off];
        kfl[khalf][d0i] = *(const bf16x8*)&KlS[off];
      }
    }
#pragma unroll
    for (int dt = 0; dt < 2; ++dt) {
      int vrow = (dt * 32 + l31) * 72;
#pragma unroll
      for (int kc = 0; kc < 4; ++kc)
        vf[dt][kc] = *(const bf16x8*)&VtS[vrow + kc * 16 + 8 * g];
    }
    asm volatile("s_waitcnt lgkmcnt(0)" ::: "memory");  // reads truly done
    __builtin_amdgcn_sched_barrier(0);
    __builtin_amdgcn_s_barrier();       // B1: all waves' reads done -> buffer free

    // --- Phase 2: stage kt+1 into the SAME buffer
    if (kt + 1 < 32) {
      int kk = kt + 1;
#pragma unroll
      for (int i = 0; i < 4; ++i) {
        int cb = (w * 4 + i) * 512;
        gload_lds16(&kbase[(size_t)kk * 4096 + r_[i] * 64 + j8_[i]], &KhS[cb]);
        gload_lds16(&lbase[(size_t)kk * 4096 + r_[i] * 64 + j8_[i]], &KlS[cb]);
        gload_lds16(&vbase[(size_t)r_[i] * 2048 + kk * 64 + j8_[i]], &VtS[cb]);
      }
      if (w == 0) {
        gload_lds16(&kbase[(size_t)kk * 4096 + r8 * 64 + j88], &KhS[8 * 512]);
        gload_lds16(&lbase[(size_t)kk * 4096 + r8 * 64 + j88], &KlS[8 * 512]);
      } else {
        gload_lds16(&vbase[(size_t)r8 * 2048 + kk * 64 + j88], &VtS[8 * 512]);
      }
    }
    __builtin_amdgcn_sched_barrier(0);

    // --- Phase 3: register-only compute.
    // S^T = mfma(K, Q): out col = l31 = q, row = crow(reg,g) = key.
    bf16x8 pa[4];
#pragma unroll
    for (int khalf = 0; khalf < 2; ++khalf) {
      f32x16 sacc;
#pragma unroll
      for (int i = 0; i < 16; ++i) sacc[i] = 0.0f;
      __builtin_amdgcn_s_setprio(1);
#pragma unroll
      for (int d0i = 0; d0i < 4; ++d0i) {
        sacc = __builtin_amdgcn_mfma_f32_32x32x16_bf16(kfh[khalf][d0i], qfh[d0i], sacc, 0, 0, 0);
        sacc = __builtin_amdgcn_mfma_f32_32x32x16_bf16(kfl[khalf][d0i], qfh[d0i], sacc, 0, 0, 0);
        sacc = __builtin_amdgcn_mfma_f32_32x32x16_bf16(kfh[khalf][d0i], qfl[d0i], sacc, 0, 0, 0);
      }
      __builtin_amdgcn_s_setprio(0);
#pragma unroll
      for (int reg = 0; reg < 16; ++reg) {
        float pvv = exp2_raw(fmaxf(sacc[reg], 0.0f) * decl2);
        rsp[reg & 3] += pvv;
        sacc[reg] = pvv;
      }
      // cvt_pk pairs -> dwords; permlane32_swap yields A-fragment words.
#pragma unroll
      for (int hf = 0; hf < 2; ++hf) {
        unsigned d0 = cvt_pk_bf16(sacc[hf * 8 + 0], sacc[hf * 8 + 1]);
        unsigned d1 = cvt_pk_bf16(sacc[hf * 8 + 2], sacc[hf * 8 + 3]);
        unsigned d2 = cvt_pk_bf16(sacc[hf * 8 + 4], sacc[hf * 8 + 5]);
        unsigned d3 = cvt_pk_bf16(sacc[hf * 8 + 6], sacc[hf * 8 + 7]);
        permlane32_swap(d0, d2);
        permlane32_swap(d1, d3);
        uint4 u; u.x = d0; u.y = d1; u.z = d2; u.w = d3;
        pa[khalf * 2 + hf] = __builtin_bit_cast(bf16x8, u);
      }
    }

    // O += P V  (P and V fully in registers)
    __builtin_amdgcn_s_setprio(1);
#pragma unroll
    for (int dt = 0; dt < 2; ++dt)
#pragma unroll
      for (int kc = 0; kc < 4; ++kc)
        oacc[dt] = __builtin_amdgcn_mfma_f32_32x32x16_bf16(pa[kc], vf[dt][kc], oacc[dt], 0, 0, 0);
    __builtin_amdgcn_s_setprio(0);

    // --- end: own loads landed (issued a compute-phase ago -> ~free wait);
    // after B2, ALL waves' loads landed => next iteration's reads are safe.
    asm volatile("s_waitcnt vmcnt(0)" ::: "memory");
    __builtin_amdgcn_s_barrier();       // B2
  }

  // row sums: combine partials, then across g halves, then LDS redistribute.
  float rs = (rsp[0] + rsp[1]) + (rsp[2] + rsp[3]);
  rs += __shfl_xor(rs, 32);
  rsS[w * 32 + l31] = rs;            // both g halves write identical value

  // normalize + write aout hi/lo [b][tok][h*64+d]
#pragma unroll
  for (int reg = 0; reg < 16; ++reg) {
    int row = (reg & 3) + 8 * (reg >> 2) + 4 * g;
    float invs = 1.0f / rsS[w * 32 + row];
    int tok = qt * 64 + w * 32 + row;
#pragma unroll
    for (int dt = 0; dt < 2; ++dt) {
      int d = dt * 32 + l31;
      ushort_t hi, lo;
      split2(oacc[dt][reg] * invs, hi, lo);
      size_t addr = ((size_t)b * 2048 + tok) * 512 + h * 64 + d;
      aoh[addr] = hi;
      aol[addr] = lo;
    }
  }
}

// ---------------------------------------------------------------------------
// Kernel E: out = aout @ Wout^T. R8-proven body + XCD-aware 1D decode.
// Exact R1 form (no prefetch, no setprio).
// ---------------------------------------------------------------------------
__global__ __launch_bounds__(256) void out_gemm_mfma(
    const ushort_t* __restrict__ ah, const ushort_t* __restrict__ al,
    const ushort_t* __restrict__ wth, const ushort_t* __restrict__ wtl,
    float* __restrict__ out) {
  __shared__ ushort_t Ah[128 * 40], Al[128 * 40], Bh[128 * 40], Bl[128 * 40];
  int tid = threadIdx.x;
  int w = tid >> 6, lane = tid & 63, l31 = lane & 31, g = lane >> 5;
  int wm = w >> 1, wn = w & 1;
  int idx = blockIdx.x;
  int xcd = idx & 7, local = idx >> 3;
  int n0 = (local & 3) * 128;
  int m0 = ((local >> 2) * 8 + xcd) * 128;

  f32x16 acc[2][2];
#pragma unroll
  for (int i = 0; i < 2; ++i)
#pragma unroll
    for (int j = 0; j < 2; ++j)
#pragma unroll
      for (int e = 0; e < 16; ++e) acc[i][j][e] = 0.0f;

  int fm[2], fc[2];
#pragma unroll
  for (int it = 0; it < 2; ++it) {
    int f = tid + it * 256;
    fm[it] = f >> 2;
    fc[it] = (f & 3) * 8;
  }

#pragma unroll 1
  for (int kt = 0; kt < 16; ++kt) {
    __syncthreads();
#pragma unroll
    for (int it = 0; it < 2; ++it) {
      size_t ao = (size_t)(m0 + fm[it]) * 512 + kt * 32 + fc[it];
      size_t bo = (size_t)(n0 + fm[it]) * 512 + kt * 32 + fc[it];
      uint4 tah = *(const uint4*)&ah[ao];
      uint4 tal = *(const uint4*)&al[ao];
      uint4 tbh = *(const uint4*)&wth[bo];
      uint4 tbl = *(const uint4*)&wtl[bo];
      int o = fm[it] * 40 + fc[it];
      *(uint4*)&Ah[o] = tah;
      *(uint4*)&Al[o] = tal;
      *(uint4*)&Bh[o] = tbh;
      *(uint4*)&Bl[o] = tbl;
    }
    __syncthreads();
#pragma unroll
    for (int kc = 0; kc < 2; ++kc) {
      int off = kc * 16 + 8 * g;
      bf16x8 afh[2], afl[2], bfh[2], bfl[2];
#pragma unroll
      for (int rb = 0; rb < 2; ++rb) {
        int r = (wm * 64 + rb * 32 + l31) * 40 + off;
        afh[rb] = *(const bf16x8*)&Ah[r];
        afl[rb] = *(const bf16x8*)&Al[r];
      }
#pragma unroll
      for (int cb = 0; cb < 2; ++cb) {
        int r = (wn * 64 + cb * 32 + l31) * 40 + off;
        bfh[cb] = *(const bf16x8*)&Bh[r];
        bfl[cb] = *(const bf16x8*)&Bl[r];
      }
#pragma unroll
      for (int rb = 0; rb < 2; ++rb)
#pragma unroll
        for (int cb = 0; cb < 2; ++cb) {
          acc[rb][cb] = __builtin_amdgcn_mfma_f32_32x32x16_bf16(afh[rb], bfh[cb], acc[rb][cb], 0, 0, 0);
          acc[rb][cb] = __builtin_amdgcn_mfma_f32_32x32x16_bf16(afh[rb], bfl[cb], acc[rb][cb], 0, 0, 0);
          acc[rb][cb] = __builtin_amdgcn_mfma_f32_32x32x16_bf16(afl[rb], bfh[cb], acc[rb][cb], 0, 0, 0);
        }
    }
  }

#pragma unroll
  for (int rb = 0; rb < 2; ++rb) {
    int m_base = m0 + wm * 64 + rb * 32;
#pragma unroll
    for (int cb = 0; cb < 2; ++cb) {
      int n_g = n0 + wn * 64 + cb * 32 + l31;
#pragma unroll
      for (int reg = 0; reg < 16; ++reg) {
        int row = (reg & 3) + 8 * (reg >> 2) + 4 * g;
        out[(size_t)(m_base + row) * 512 + n_g] = acc[rb][cb][reg];
      }
    }
  }
}

// ---------------------------------------------------------------------------
extern "C" void kernel_launch(void* const* d_in, const int* in_sizes, int n_in,
                              void* d_out, int out_size, void* d_ws, size_t ws_size,
                              hipStream_t stream) {
  (void)in_sizes; (void)n_in;
  const float* x     = (const float*)d_in[0];
  const float* R     = (const float*)d_in[1];
  const float* gamma = (const float*)d_in[2];
  const float* beta  = (const float*)d_in[3];
  const float* Wqkv  = (const float*)d_in[4];
  const float* Wout  = (const float*)d_in[5];
  const float* av    = (const float*)d_in[6];
  const float* cv    = (const float*)d_in[7];
  float* out = (float*)d_out;

  const size_t EL  = (size_t)B_ * N_ * DIM_;     // 4,194,304 elements
  const size_t SZT = EL * sizeof(ushort_t);      // 8 MiB per bf16 tensor

  char* p = (char*)d_ws;
  ushort_t* wqh = (ushort_t*)p;                  p += (size_t)1536 * 512 * 2;
  ushort_t* wql = (ushort_t*)p;                  p += (size_t)1536 * 512 * 2;
  ushort_t* woh = (ushort_t*)p;                  p += (size_t)512 * 512 * 2;
  ushort_t* wol = (ushort_t*)p;                  p += (size_t)512 * 512 * 2;
  ushort_t* qhb = (ushort_t*)p;                  p += SZT;
  ushort_t* qlb = (ushort_t*)p;                  p += SZT;
  ushort_t* khb = (ushort_t*)p;                  p += SZT;
  ushort_t* klb = (ushort_t*)p;                  p += SZT;
  ushort_t* vtb = (ushort_t*)p;                  p += SZT;
  size_t base_need = (size_t)(p - (char*)d_ws);
  size_t needA = base_need + 2 * SZT;

  bool planA = (ws_size >= needA);
  ushort_t* xnh = planA ? (ushort_t*)p : (ushort_t*)d_out;
  ushort_t* xnl = xnh + EL;
  float* gemm_dst = planA ? out : (float*)qhb;

  prep_kernel<<<dim3(2304), dim3(256), 0, stream>>>(x, gamma, beta, Wqkv, Wout,
                                                    xnh, xnl, wqh, wql, woh, wol);
  qkv_gemm_mfma<<<dim3(768), dim3(256), 0, stream>>>(xnh, xnl, wqh, wql,
                                                     qhb, qlb, khb, klb, vtb);
  attn_mfma<<<dim3(32, 32), dim3(128), 0, stream>>>(qhb, qlb, khb, klb, vtb,
                                                    R, av, cv, xnh, xnl);
  out_gemm_mfma<<<dim3(256), dim3(256), 0, stream>>>(xnh, xnl, woh, wol, gemm_dst);
  if (!planA) {
    hipMemcpyAsync(out, gemm_dst, (size_t)out_size * sizeof(float),
                   hipMemcpyDeviceToDevice, stream);
  }
}

// Round 7
// 229.039 us; speedup vs baseline: 1.0549x; 1.0549x over previous
//
#include <hip/hip_runtime.h>
#include <math.h>

#define B_   4
#define N_   2048
#define DIM_ 512
#define T_   16
#define H_   8
#define DH_  64
// num_patches = 128; 64-token tiles align within patches -> decay scalar per tile pair

typedef unsigned short ushort_t;
typedef __attribute__((ext_vector_type(8))) short bf16x8;    // 8 bf16 = 4 VGPRs
typedef __attribute__((ext_vector_type(16))) float f32x16;   // 32x32 MFMA acc

__device__ inline ushort_t bf16_rn(float x) {
  unsigned u = __builtin_bit_cast(unsigned, x);
  u += 0x7FFFu + ((u >> 16) & 1u);
  return (ushort_t)(u >> 16);
}
__device__ inline float bf16f(ushort_t h) {
  return __builtin_bit_cast(float, (unsigned)h << 16);
}
__device__ inline unsigned pack2(ushort_t a, ushort_t b) {
  return (unsigned)a | ((unsigned)b << 16);
}
__device__ inline void split2(float x, ushort_t &h, ushort_t &l) {
  h = bf16_rn(x);
  l = bf16_rn(x - bf16f(h));
}
// v_cvt_pk_bf16_f32: D = {lo: bf16(lo), hi: bf16(hi)}, RNE (same bits as bf16_rn)
__device__ inline unsigned cvt_pk_bf16(float lo, float hi) {
  unsigned r;
  asm("v_cvt_pk_bf16_f32 %0, %1, %2" : "=v"(r) : "v"(lo), "v"(hi));
  return r;
}
// v_permlane32_swap_b32: x.hi32lanes <-> y.lo32lanes
__device__ inline void permlane32_swap(unsigned &x, unsigned &y) {
  asm volatile("v_permlane32_swap_b32 %0, %1" : "+v"(x), "+v"(y));
}
// raw v_exp_f32 (2^x): args here are >=0 and normal-range -> identical result
// bits to exp2f, without OCML's wrapper instructions (verified R6: absmax same)
__device__ inline float exp2_raw(float x) {
  float r;
  asm("v_exp_f32 %0, %1" : "=v"(r) : "v"(x));
  return r;
}
// async global->LDS, 16B per lane; LDS dest = wave-uniform base + lane*16
__device__ inline void gload_lds16(const ushort_t* g, ushort_t* l) {
  __builtin_amdgcn_global_load_lds(
      (const __attribute__((address_space(1))) unsigned int*)(g),
      (__attribute__((address_space(3))) unsigned int*)(l),
      16, 0, 0);
}

// ---------------------------------------------------------------------------
// Kernel A: merged prep. Blocks 0..191: Wqkv transpose+split; 192..255: Wout;
// 256..2303: LayerNorm -> xn hi/lo.
// ---------------------------------------------------------------------------
__global__ __launch_bounds__(256) void prep_kernel(
    const float* __restrict__ x, const float* __restrict__ gamma,
    const float* __restrict__ beta, const float* __restrict__ Wqkv,
    const float* __restrict__ Wout,
    ushort_t* __restrict__ xnh, ushort_t* __restrict__ xnl,
    ushort_t* __restrict__ wqh, ushort_t* __restrict__ wql,
    ushort_t* __restrict__ woh, ushort_t* __restrict__ wol) {
  __shared__ float Ts[64][68];
  int bidx = blockIdx.x;
  int tid = threadIdx.x;
  if (bidx < 256) {
    const float* src; ushort_t* dh; ushort_t* dl; int Nn, n0, k0;
    if (bidx < 192) {
      src = Wqkv; dh = wqh; dl = wql; Nn = 1536;
      n0 = (bidx % 24) * 64; k0 = (bidx / 24) * 64;
    } else {
      int l = bidx - 192;
      src = Wout; dh = woh; dl = wol; Nn = 512;
      n0 = (l % 8) * 64; k0 = (l / 8) * 64;
    }
#pragma unroll
    for (int it = 0; it < 4; ++it) {
      int idx = tid + it * 256;
      int r = idx >> 4, c4 = (idx & 15) * 4;
      *(float4*)&Ts[r][c4] = *(const float4*)&src[(size_t)(k0 + r) * Nn + n0 + c4];
    }
    __syncthreads();
#pragma unroll
    for (int it = 0; it < 2; ++it) {
      int idx = tid + it * 256;
      int n = idx >> 3, kc = (idx & 7) * 8;
      ushort_t hs[8], ls[8];
#pragma unroll
      for (int j = 0; j < 8; ++j) split2(Ts[kc + j][n], hs[j], ls[j]);
      uint4 uh, ul;
      uh.x = pack2(hs[0], hs[1]); uh.y = pack2(hs[2], hs[3]);
      uh.z = pack2(hs[4], hs[5]); uh.w = pack2(hs[6], hs[7]);
      ul.x = pack2(ls[0], ls[1]); ul.y = pack2(ls[2], ls[3]);
      ul.z = pack2(ls[4], ls[5]); ul.w = pack2(ls[6], ls[7]);
      size_t o = (size_t)(n0 + n) * 512 + k0 + kc;
      *(uint4*)&dh[o] = uh;
      *(uint4*)&dl[o] = ul;
    }
  } else {
    int row  = (bidx - 256) * 4 + (tid >> 6);
    int lane = tid & 63;
    const float4* xr = (const float4*)(x + (size_t)row * DIM_);
    float4 v0 = xr[lane * 2 + 0];
    float4 v1 = xr[lane * 2 + 1];
    float s  = v0.x + v0.y + v0.z + v0.w + v1.x + v1.y + v1.z + v1.w;
    float ss = v0.x*v0.x + v0.y*v0.y + v0.z*v0.z + v0.w*v0.w
             + v1.x*v1.x + v1.y*v1.y + v1.z*v1.z + v1.w*v1.w;
#pragma unroll
    for (int off = 32; off > 0; off >>= 1) {
      s  += __shfl_xor(s, off);
      ss += __shfl_xor(ss, off);
    }
    float mu  = s * (1.0f / DIM_);
    float var = ss * (1.0f / DIM_) - mu * mu;
    float rstd = rsqrtf(var + 1e-5f);
    float4 g0 = *(const float4*)&gamma[lane * 8];
    float4 g1 = *(const float4*)&gamma[lane * 8 + 4];
    float4 b0 = *(const float4*)&beta[lane * 8];
    float4 b1 = *(const float4*)&beta[lane * 8 + 4];
    float xv[8] = {v0.x, v0.y, v0.z, v0.w, v1.x, v1.y, v1.z, v1.w};
    float gv[8] = {g0.x, g0.y, g0.z, g0.w, g1.x, g1.y, g1.z, g1.w};
    float bv[8] = {b0.x, b0.y, b0.z, b0.w, b1.x, b1.y, b1.z, b1.w};
    ushort_t hs[8], ls[8];
#pragma unroll
    for (int j = 0; j < 8; ++j) {
      float xn = (xv[j] - mu) * rstd * gv[j] + bv[j];
      split2(xn, hs[j], ls[j]);
    }
    uint4 uh, ul;
    uh.x = pack2(hs[0], hs[1]); uh.y = pack2(hs[2], hs[3]);
    uh.z = pack2(hs[4], hs[5]); uh.w = pack2(hs[6], hs[7]);
    ul.x = pack2(ls[0], ls[1]); ul.y = pack2(ls[2], ls[3]);
    ul.z = pack2(ls[4], ls[5]); ul.w = pack2(ls[6], ls[7]);
    size_t o = (size_t)row * DIM_ + lane * 8;
    *(uint4*)&xnh[o] = uh;
    *(uint4*)&xnl[o] = ul;
  }
}

// ---------------------------------------------------------------------------
// Kernel C: qkv = xn @ Wqkv^T. R8 compute body + XCD decode; staging via
// direct global_load_lds on the [128][40] padded layout (80B row = 5 x 16B
// slots, slot 4 = pad duplicate; 10 x 1KiB chunks per array). Wave w stages
// exactly one array (w0:Ah w1:Al w2:Bh w3:Bl) = 10 gload insts, replacing
// 4 global loads + 4 ds_write_b128 PER THREAD (Common-mistake #1 lever).
// Schedule unchanged: sync; stage; sync (vmcnt0 drain, m97 pattern); compute.
// ---------------------------------------------------------------------------
__global__ __launch_bounds__(256) void qkv_gemm_mfma(
    const ushort_t* __restrict__ xnh, const ushort_t* __restrict__ xnl,
    const ushort_t* __restrict__ wth, const ushort_t* __restrict__ wtl,
    ushort_t* __restrict__ qh, ushort_t* __restrict__ ql,
    ushort_t* __restrict__ kho, ushort_t* __restrict__ klo,
    ushort_t* __restrict__ vt) {
  __shared__ __align__(16) ushort_t Ah[128 * 40];
  __shared__ __align__(16) ushort_t Al[128 * 40];
  __shared__ __align__(16) ushort_t Bh[128 * 40];
  __shared__ __align__(16) ushort_t Bl[128 * 40];
  int tid = threadIdx.x;
  int w = tid >> 6, lane = tid & 63, l31 = lane & 31, g = lane >> 5;
  int wm = w >> 1, wn = w & 1;
  int idx = blockIdx.x;
  int xcd = idx & 7, local = idx >> 3;
  int n0 = (local % 12) * 128;
  int m0 = ((local / 12) * 8 + xcd) * 128;

  f32x16 acc[2][2];
#pragma unroll
  for (int i = 0; i < 2; ++i)
#pragma unroll
    for (int j = 0; j < 2; ++j)
#pragma unroll
      for (int e = 0; e < 16; ++e) acc[i][j][e] = 0.0f;

  // staging map: chunk ci, lane l covers ushort u = ci*512 + l*8 of the
  // padded array -> row r = u/40, slot j = (u%40)/8 (4 = pad -> duplicate).
  int rowbase = (w < 2) ? m0 : n0;
  int off_[10];
#pragma unroll
  for (int ci = 0; ci < 10; ++ci) {
    int u = ci * 512 + lane * 8;
    int r = u / 40;
    int j = (u - r * 40) >> 3;
    off_[ci] = (rowbase + r) * 512 + ((j == 4) ? 0 : (j << 3));
  }

#pragma unroll 1
  for (int kt = 0; kt < 16; ++kt) {
    __syncthreads();
    if (w == 0) {
#pragma unroll
      for (int ci = 0; ci < 10; ++ci)
        gload_lds16(&xnh[(size_t)off_[ci] + kt * 32], &Ah[ci * 512]);
    } else if (w == 1) {
#pragma unroll
      for (int ci = 0; ci < 10; ++ci)
        gload_lds16(&xnl[(size_t)off_[ci] + kt * 32], &Al[ci * 512]);
    } else if (w == 2) {
#pragma unroll
      for (int ci = 0; ci < 10; ++ci)
        gload_lds16(&wth[(size_t)off_[ci] + kt * 32], &Bh[ci * 512]);
    } else {
#pragma unroll
      for (int ci = 0; ci < 10; ++ci)
        gload_lds16(&wtl[(size_t)off_[ci] + kt * 32], &Bl[ci * 512]);
    }
    __syncthreads();
#pragma unroll
    for (int kc = 0; kc < 2; ++kc) {
      int off = kc * 16 + 8 * g;
      bf16x8 afh[2], afl[2], bfh[2], bfl[2];
#pragma unroll
      for (int rb = 0; rb < 2; ++rb) {
        int r = (wm * 64 + rb * 32 + l31) * 40 + off;
        afh[rb] = *(const bf16x8*)&Ah[r];
        afl[rb] = *(const bf16x8*)&Al[r];
      }
#pragma unroll
      for (int cb = 0; cb < 2; ++cb) {
        int r = (wn * 64 + cb * 32 + l31) * 40 + off;
        bfh[cb] = *(const bf16x8*)&Bh[r];
        bfl[cb] = *(const bf16x8*)&Bl[r];
      }
#pragma unroll
      for (int rb = 0; rb < 2; ++rb)
#pragma unroll
        for (int cb = 0; cb < 2; ++cb) {
          acc[rb][cb] = __builtin_amdgcn_mfma_f32_32x32x16_bf16(afh[rb], bfh[cb], acc[rb][cb], 0, 0, 0);
          acc[rb][cb] = __builtin_amdgcn_mfma_f32_32x32x16_bf16(afh[rb], bfl[cb], acc[rb][cb], 0, 0, 0);
          acc[rb][cb] = __builtin_amdgcn_mfma_f32_32x32x16_bf16(afl[rb], bfh[cb], acc[rb][cb], 0, 0, 0);
        }
    }
  }

  int part = n0 >> 9;
#pragma unroll
  for (int rb = 0; rb < 2; ++rb) {
    int m_base = m0 + wm * 64 + rb * 32;
#pragma unroll
    for (int cb = 0; cb < 2; ++cb) {
      int n_g = n0 + wn * 64 + cb * 32 + l31;
      int rem = n_g & 511, hh = rem >> 6, d = rem & 63;
      if (part == 2) {
#pragma unroll
        for (int grp = 0; grp < 4; ++grp) {
          int m_g = m_base + grp * 8 + 4 * g;
          int bb = m_g >> 11, tok = m_g & 2047;
          uint2 pk;
          pk.x = pack2(bf16_rn(acc[rb][cb][grp * 4 + 0]), bf16_rn(acc[rb][cb][grp * 4 + 1]));
          pk.y = pack2(bf16_rn(acc[rb][cb][grp * 4 + 2]), bf16_rn(acc[rb][cb][grp * 4 + 3]));
          *(uint2*)&vt[((size_t)(bb * 8 + hh) * 64 + d) * 2048 + tok] = pk;
        }
      } else {
        float sc = (part == 0) ? 0.125f : 1.0f;
        ushort_t* dsth = (part == 0) ? qh : kho;
        ushort_t* dstl = (part == 0) ? ql : klo;
#pragma unroll
        for (int reg = 0; reg < 16; ++reg) {
          int row = (reg & 3) + 8 * (reg >> 2) + 4 * g;
          int m_g = m_base + row;
          int bb = m_g >> 11, tok = m_g & 2047;
          ushort_t hi, lo;
          split2(acc[rb][cb][reg] * sc, hi, lo);
          size_t addr = ((size_t)(bb * 8 + hh) * 2048 + tok) * 64 + d;
          dsth[addr] = hi;
          dstl[addr] = lo;
        }
      }
    }
  }
}

// ---------------------------------------------------------------------------
// Kernel D: MFMA attention — REVERT to the R5-measured 92.2 us version
// (128 q / 4 waves, double-buffered K/V, m201 phase order, ONE barrier/kt)
// with two local hardenings: raw v_exp_f32 (OCML wrapper removed; verified
// identical in R6) and explicit vmcnt(0) before the barrier (loads issued a
// full compute-phase ago -> ~free; closes the cross-wave staging race).
// ---------------------------------------------------------------------------
__global__ __launch_bounds__(256, 2) void attn_mfma(
    const ushort_t* __restrict__ qh, const ushort_t* __restrict__ ql,
    const ushort_t* __restrict__ kho, const ushort_t* __restrict__ klo,
    const ushort_t* __restrict__ vt, const float* __restrict__ R,
    const float* __restrict__ a, const float* __restrict__ c,
    ushort_t* __restrict__ aoh, ushort_t* __restrict__ aol) {
  __shared__ __align__(16) ushort_t KhS[2 * 4608];
  __shared__ __align__(16) ushort_t KlS[2 * 4608];
  __shared__ __align__(16) ushort_t VtS[2 * 4608];
  __shared__ float rsS[128];
  __shared__ float decl2S[16];

  int tid = threadIdx.x;
  int w = tid >> 6, lane = tid & 63, l31 = lane & 31, g = lane >> 5;
  int bh = blockIdx.x;
  int qt = blockIdx.y;               // 128-query tile == timepoint index
  int b = bh >> 3, h = bh & 7;

  // Q fragments: wave w owns rows qt*128 + w*32 .. +32 (q = l31 -> B operand col)
  int qrow = qt * 128 + w * 32 + l31;
  size_t qoff = ((size_t)bh * 2048 + qrow) * 64;
  bf16x8 qfh[4], qfl[4];
#pragma unroll
  for (int d0i = 0; d0i < 4; ++d0i) {
    qfh[d0i] = *(const bf16x8*)&qh[qoff + d0i * 16 + 8 * g];
    qfl[d0i] = *(const bf16x8*)&ql[qoff + d0i * 16 + 8 * g];
  }

  const ushort_t* kbase = kho + (size_t)bh * 2048 * 64;
  const ushort_t* lbase = klo + (size_t)bh * 2048 * 64;
  const ushort_t* vbase = vt + (size_t)bh * 64 * 2048;

  // decay table: 16 kt-pairs, log2e folded in
  if (tid < 16) {
    float aab = fabsf(a[h]);
    float cab = fabsf(c[h]);
    float Rv = R[b * (T_ * T_) + qt * T_ + tid];
    decl2S[tid] = 1.4426950408889634f / (1.0f + __expf(aab * Rv - cab));
  }

  // padded-stride staging map: per chunk, per lane -> (row r, slot-offset j8)
  int r_[3], j8_[3];
#pragma unroll
  for (int i = 0; i < 3; ++i) {
    int ch = (i < 2) ? (w + i * 4) : 8;
    int u = ch * 512 + lane * 8;          // ushort index in padded array
    int r = u / 72;                        // 0..63
    int j = (u - r * 72) >> 3;             // 0..8 (8 = pad slot)
    r_[i] = r;
    j8_[i] = (j == 8) ? 0 : (j << 3);      // pad: duplicate row-start fetch
  }
  int a8 = (w < 3) ? w : 0;                // which array this wave's chunk-8 is

  f32x16 oacc[2];
#pragma unroll
  for (int t = 0; t < 2; ++t)
#pragma unroll
    for (int i = 0; i < 16; ++i) oacc[t][i] = 0.0f;
  float rsp[4] = {0.0f, 0.0f, 0.0f, 0.0f};

  // prologue: stage kt=0 into buf 0 (7 gloads); __syncthreads drains fully
  {
#pragma unroll
    for (int i = 0; i < 2; ++i) {
      int cb = (w + i * 4) * 512;
      gload_lds16(&kbase[(size_t)r_[i] * 64 + j8_[i]], &KhS[cb]);
      gload_lds16(&lbase[(size_t)r_[i] * 64 + j8_[i]], &KlS[cb]);
      gload_lds16(&vbase[(size_t)r_[i] * 2048 + j8_[i]], &VtS[cb]);
    }
    int cb8 = 8 * 512;
    if (a8 == 0)      gload_lds16(&kbase[(size_t)r_[2] * 64 + j8_[2]], &KhS[cb8]);
    else if (a8 == 1) gload_lds16(&lbase[(size_t)r_[2] * 64 + j8_[2]], &KlS[cb8]);
    else              gload_lds16(&vbase[(size_t)r_[2] * 2048 + j8_[2]], &VtS[cb8]);
  }
  __syncthreads();

  int cur = 0;

#pragma unroll 1
  for (int kt = 0; kt < 32; ++kt) {
    int kb = cur * 4608;

    // --- Phase 1: ds_read ALL fragments of buf[cur] into registers.
    float decl2 = decl2S[kt >> 1];
    bf16x8 kfh[2][4], kfl[2][4], vf[2][4];
#pragma unroll
    for (int khalf = 0; khalf < 2; ++khalf) {
      int krow = kb + (khalf * 32 + l31) * 72;
#pragma unroll
      for (int d0i = 0; d0i < 4; ++d0i) {
        int off = krow + d0i * 16 + 8 * g;
        kfh[khalf][d0i] = *(const bf16x8*)&KhS[off];
        kfl[khalf][d0i] = *(const bf16x8*)&KlS[off];
      }
    }
#pragma unroll
    for (int dt = 0; dt < 2; ++dt) {
      int vrow = kb + (dt * 32 + l31) * 72;
#pragma unroll
      for (int kc = 0; kc < 4; ++kc)
        vf[dt][kc] = *(const bf16x8*)&VtS[vrow + kc * 16 + 8 * g];
    }
    __builtin_amdgcn_sched_barrier(0);

    // --- Phase 2: stage kt+1 into buf cur^1 (no LDS read follows this)
    if (kt + 1 < 32) {
      int lb = (cur ^ 1) * 4608;
      int kk = kt + 1;
#pragma unroll
      for (int i = 0; i < 2; ++i) {
        int cb = lb + (w + i * 4) * 512;
        gload_lds16(&kbase[(size_t)kk * 4096 + r_[i] * 64 + j8_[i]], &KhS[cb]);
        gload_lds16(&lbase[(size_t)kk * 4096 + r_[i] * 64 + j8_[i]], &KlS[cb]);
        gload_lds16(&vbase[(size_t)r_[i] * 2048 + kk * 64 + j8_[i]], &VtS[cb]);
      }
      int cb8 = lb + 8 * 512;
      if (a8 == 0)      gload_lds16(&kbase[(size_t)kk * 4096 + r_[2] * 64 + j8_[2]], &KhS[cb8]);
      else if (a8 == 1) gload_lds16(&lbase[(size_t)kk * 4096 + r_[2] * 64 + j8_[2]], &KlS[cb8]);
      else              gload_lds16(&vbase[(size_t)r_[2] * 2048 + kk * 64 + j8_[2]], &VtS[cb8]);
    }
    __builtin_amdgcn_sched_barrier(0);

    // --- Phase 3: register-only compute.
    // S^T = mfma(K, Q): out col = l31 = q, row = crow(reg,g) = key.
    bf16x8 pa[4];
#pragma unroll
    for (int khalf = 0; khalf < 2; ++khalf) {
      f32x16 sacc;
#pragma unroll
      for (int i = 0; i < 16; ++i) sacc[i] = 0.0f;
#pragma unroll
      for (int d0i = 0; d0i < 4; ++d0i) {
        sacc = __builtin_amdgcn_mfma_f32_32x32x16_bf16(kfh[khalf][d0i], qfh[d0i], sacc, 0, 0, 0);
        sacc = __builtin_amdgcn_mfma_f32_32x32x16_bf16(kfl[khalf][d0i], qfh[d0i], sacc, 0, 0, 0);
        sacc = __builtin_amdgcn_mfma_f32_32x32x16_bf16(kfh[khalf][d0i], qfl[d0i], sacc, 0, 0, 0);
      }
#pragma unroll
      for (int reg = 0; reg < 16; ++reg) {
        float pvv = exp2_raw(fmaxf(sacc[reg], 0.0f) * decl2);
        rsp[reg & 3] += pvv;
        sacc[reg] = pvv;
      }
      // cvt_pk pairs -> dwords; permlane32_swap yields A-fragment words.
#pragma unroll
      for (int hf = 0; hf < 2; ++hf) {
        unsigned d0 = cvt_pk_bf16(sacc[hf * 8 + 0], sacc[hf * 8 + 1]);
        unsigned d1 = cvt_pk_bf16(sacc[hf * 8 + 2], sacc[hf * 8 + 3]);
        unsigned d2 = cvt_pk_bf16(sacc[hf * 8 + 4], sacc[hf * 8 + 5]);
        unsigned d3 = cvt_pk_bf16(sacc[hf * 8 + 6], sacc[hf * 8 + 7]);
        permlane32_swap(d0, d2);
        permlane32_swap(d1, d3);
        uint4 u; u.x = d0; u.y = d1; u.z = d2; u.w = d3;
        pa[khalf * 2 + hf] = __builtin_bit_cast(bf16x8, u);
      }
    }

    // O += P V  (P and V fully in registers)
#pragma unroll
    for (int dt = 0; dt < 2; ++dt)
#pragma unroll
      for (int kc = 0; kc < 4; ++kc)
        oacc[dt] = __builtin_amdgcn_mfma_f32_32x32x16_bf16(pa[kc], vf[dt][kc], oacc[dt], 0, 0, 0);

    // own loads were issued a full compute-phase ago -> wait ~free; after the
    // barrier ALL waves' loads have landed => next iteration's reads safe.
    asm volatile("s_waitcnt vmcnt(0)" ::: "memory");
    __builtin_amdgcn_s_barrier();
    cur ^= 1;
  }

  // row sums: combine partials, then across g halves, then LDS redistribute.
  float rs = (rsp[0] + rsp[1]) + (rsp[2] + rsp[3]);
  rs += __shfl_xor(rs, 32);
  rsS[w * 32 + l31] = rs;            // both g halves write identical value

  // normalize + write aout hi/lo [b][tok][h*64+d]
#pragma unroll
  for (int reg = 0; reg < 16; ++reg) {
    int row = (reg & 3) + 8 * (reg >> 2) + 4 * g;
    float invs = 1.0f / rsS[w * 32 + row];
    int tok = qt * 128 + w * 32 + row;
#pragma unroll
    for (int dt = 0; dt < 2; ++dt) {
      int d = dt * 32 + l31;
      ushort_t hi, lo;
      split2(oacc[dt][reg] * invs, hi, lo);
      size_t addr = ((size_t)b * 2048 + tok) * 512 + h * 64 + d;
      aoh[addr] = hi;
      aol[addr] = lo;
    }
  }
}

// ---------------------------------------------------------------------------
// Kernel E: out = aout @ Wout^T. Same gload_lds staging conversion as qkv.
// ---------------------------------------------------------------------------
__global__ __launch_bounds__(256) void out_gemm_mfma(
    const ushort_t* __restrict__ ah, const ushort_t* __restrict__ al,
    const ushort_t* __restrict__ wth, const ushort_t* __restrict__ wtl,
    float* __restrict__ out) {
  __shared__ __align__(16) ushort_t Ah[128 * 40];
  __shared__ __align__(16) ushort_t Al[128 * 40];
  __shared__ __align__(16) ushort_t Bh[128 * 40];
  __shared__ __align__(16) ushort_t Bl[128 * 40];
  int tid = threadIdx.x;
  int w = tid >> 6, lane = tid & 63, l31 = lane & 31, g = lane >> 5;
  int wm = w >> 1, wn = w & 1;
  int idx = blockIdx.x;
  int xcd = idx & 7, local = idx >> 3;
  int n0 = (local & 3) * 128;
  int m0 = ((local >> 2) * 8 + xcd) * 128;

  f32x16 acc[2][2];
#pragma unroll
  for (int i = 0; i < 2; ++i)
#pragma unroll
    for (int j = 0; j < 2; ++j)
#pragma unroll
      for (int e = 0; e < 16; ++e) acc[i][j][e] = 0.0f;

  int rowbase = (w < 2) ? m0 : n0;
  int off_[10];
#pragma unroll
  for (int ci = 0; ci < 10; ++ci) {
    int u = ci * 512 + lane * 8;
    int r = u / 40;
    int j = (u - r * 40) >> 3;
    off_[ci] = (rowbase + r) * 512 + ((j == 4) ? 0 : (j << 3));
  }

#pragma unroll 1
  for (int kt = 0; kt < 16; ++kt) {
    __syncthreads();
    if (w == 0) {
#pragma unroll
      for (int ci = 0; ci < 10; ++ci)
        gload_lds16(&ah[(size_t)off_[ci] + kt * 32], &Ah[ci * 512]);
    } else if (w == 1) {
#pragma unroll
      for (int ci = 0; ci < 10; ++ci)
        gload_lds16(&al[(size_t)off_[ci] + kt * 32], &Al[ci * 512]);
    } else if (w == 2) {
#pragma unroll
      for (int ci = 0; ci < 10; ++ci)
        gload_lds16(&wth[(size_t)off_[ci] + kt * 32], &Bh[ci * 512]);
    } else {
#pragma unroll
      for (int ci = 0; ci < 10; ++ci)
        gload_lds16(&wtl[(size_t)off_[ci] + kt * 32], &Bl[ci * 512]);
    }
    __syncthreads();
#pragma unroll
    for (int kc = 0; kc < 2; ++kc) {
      int off = kc * 16 + 8 * g;
      bf16x8 afh[2], afl[2], bfh[2], bfl[2];
#pragma unroll
      for (int rb = 0; rb < 2; ++rb) {
        int r = (wm * 64 + rb * 32 + l31) * 40 + off;
        afh[rb] = *(const bf16x8*)&Ah[r];
        afl[rb] = *(const bf16x8*)&Al[r];
      }
#pragma unroll
      for (int cb = 0; cb < 2; ++cb) {
        int r = (wn * 64 + cb * 32 + l31) * 40 + off;
        bfh[cb] = *(const bf16x8*)&Bh[r];
        bfl[cb] = *(const bf16x8*)&Bl[r];
      }
#pragma unroll
      for (int rb = 0; rb < 2; ++rb)
#pragma unroll
        for (int cb = 0; cb < 2; ++cb) {
          acc[rb][cb] = __builtin_amdgcn_mfma_f32_32x32x16_bf16(afh[rb], bfh[cb], acc[rb][cb], 0, 0, 0);
          acc[rb][cb] = __builtin_amdgcn_mfma_f32_32x32x16_bf16(afh[rb], bfl[cb], acc[rb][cb], 0, 0, 0);
          acc[rb][cb] = __builtin_amdgcn_mfma_f32_32x32x16_bf16(afl[rb], bfh[cb], acc[rb][cb], 0, 0, 0);
        }
    }
  }

#pragma unroll
  for (int rb = 0; rb < 2; ++rb) {
    int m_base = m0 + wm * 64 + rb * 32;
#pragma unroll
    for (int cb = 0; cb < 2; ++cb) {
      int n_g = n0 + wn * 64 + cb * 32 + l31;
#pragma unroll
      for (int reg = 0; reg < 16; ++reg) {
        int row = (reg & 3) + 8 * (reg >> 2) + 4 * g;
        out[(size_t)(m_base + row) * 512 + n_g] = acc[rb][cb][reg];
      }
    }
  }
}

// ---------------------------------------------------------------------------
extern "C" void kernel_launch(void* const* d_in, const int* in_sizes, int n_in,
                              void* d_out, int out_size, void* d_ws, size_t ws_size,
                              hipStream_t stream) {
  (void)in_sizes; (void)n_in;
  const float* x     = (const float*)d_in[0];
  const float* R     = (const float*)d_in[1];
  const float* gamma = (const float*)d_in[2];
  const float* beta  = (const float*)d_in[3];
  const float* Wqkv  = (const float*)d_in[4];
  const float* Wout  = (const float*)d_in[5];
  const float* av    = (const float*)d_in[6];
  const float* cv    = (const float*)d_in[7];
  float* out = (float*)d_out;

  const size_t EL  = (size_t)B_ * N_ * DIM_;     // 4,194,304 elements
  const size_t SZT = EL * sizeof(ushort_t);      // 8 MiB per bf16 tensor

  char* p = (char*)d_ws;
  ushort_t* wqh = (ushort_t*)p;                  p += (size_t)1536 * 512 * 2;
  ushort_t* wql = (ushort_t*)p;                  p += (size_t)1536 * 512 * 2;
  ushort_t* woh = (ushort_t*)p;                  p += (size_t)512 * 512 * 2;
  ushort_t* wol = (ushort_t*)p;                  p += (size_t)512 * 512 * 2;
  ushort_t* qhb = (ushort_t*)p;                  p += SZT;
  ushort_t* qlb = (ushort_t*)p;                  p += SZT;
  ushort_t* khb = (ushort_t*)p;                  p += SZT;
  ushort_t* klb = (ushort_t*)p;                  p += SZT;
  ushort_t* vtb = (ushort_t*)p;                  p += SZT;
  size_t base_need = (size_t)(p - (char*)d_ws);
  size_t needA = base_need + 2 * SZT;

  bool planA = (ws_size >= needA);
  ushort_t* xnh = planA ? (ushort_t*)p : (ushort_t*)d_out;
  ushort_t* xnl = xnh + EL;
  float* gemm_dst = planA ? out : (float*)qhb;

  prep_kernel<<<dim3(2304), dim3(256), 0, stream>>>(x, gamma, beta, Wqkv, Wout,
                                                    xnh, xnl, wqh, wql, woh, wol);
  qkv_gemm_mfma<<<dim3(768), dim3(256), 0, stream>>>(xnh, xnl, wqh, wql,
                                                     qhb, qlb, khb, klb, vtb);
  attn_mfma<<<dim3(32, 16), dim3(256), 0, stream>>>(qhb, qlb, khb, klb, vtb,
                                                    R, av, cv, xnh, xnl);
  out_gemm_mfma<<<dim3(256), dim3(256), 0, stream>>>(xnh, xnl, woh, wol, gemm_dst);
  if (!planA) {
    hipMemcpyAsync(out, gemm_dst, (size_t)out_size * sizeof(float),
                   hipMemcpyDeviceToDevice, stream);
  }
}

// Round 8
// 223.113 us; speedup vs baseline: 1.0829x; 1.0266x over previous
//
#include <hip/hip_runtime.h>
#include <math.h>

#define B_   4
#define N_   2048
#define DIM_ 512
#define T_   16
#define H_   8
#define DH_  64
// num_patches = 128; 64-token tiles align within patches -> decay scalar per tile pair

typedef unsigned short ushort_t;
typedef __attribute__((ext_vector_type(8))) short bf16x8;    // 8 bf16 = 4 VGPRs
typedef __attribute__((ext_vector_type(16))) float f32x16;   // 32x32 MFMA acc

__device__ inline ushort_t bf16_rn(float x) {
  unsigned u = __builtin_bit_cast(unsigned, x);
  u += 0x7FFFu + ((u >> 16) & 1u);
  return (ushort_t)(u >> 16);
}
__device__ inline float bf16f(ushort_t h) {
  return __builtin_bit_cast(float, (unsigned)h << 16);
}
__device__ inline unsigned pack2(ushort_t a, ushort_t b) {
  return (unsigned)a | ((unsigned)b << 16);
}
__device__ inline void split2(float x, ushort_t &h, ushort_t &l) {
  h = bf16_rn(x);
  l = bf16_rn(x - bf16f(h));
}
// v_cvt_pk_bf16_f32: D = {lo: bf16(lo), hi: bf16(hi)}, RNE (same bits as bf16_rn)
__device__ inline unsigned cvt_pk_bf16(float lo, float hi) {
  unsigned r;
  asm("v_cvt_pk_bf16_f32 %0, %1, %2" : "=v"(r) : "v"(lo), "v"(hi));
  return r;
}
// v_permlane32_swap_b32: x.hi32lanes <-> y.lo32lanes
__device__ inline void permlane32_swap(unsigned &x, unsigned &y) {
  asm volatile("v_permlane32_swap_b32 %0, %1" : "+v"(x), "+v"(y));
}
// raw v_exp_f32 (2^x): args here are >=0 and normal-range -> identical result
// bits to exp2f, without OCML's wrapper instructions (verified R6/R7)
__device__ inline float exp2_raw(float x) {
  float r;
  asm("v_exp_f32 %0, %1" : "=v"(r) : "v"(x));
  return r;
}
// async global->LDS, 16B per lane; LDS dest = wave-uniform base + lane*16
__device__ inline void gload_lds16(const ushort_t* g, ushort_t* l) {
  __builtin_amdgcn_global_load_lds(
      (const __attribute__((address_space(1))) unsigned int*)(g),
      (__attribute__((address_space(3))) unsigned int*)(l),
      16, 0, 0);
}

// ---------------------------------------------------------------------------
// Kernel A: merged prep. Blocks 0..191: Wqkv transpose+split; 192..255: Wout;
// 256..2303: LayerNorm -> xn hi/lo.
// ---------------------------------------------------------------------------
__global__ __launch_bounds__(256) void prep_kernel(
    const float* __restrict__ x, const float* __restrict__ gamma,
    const float* __restrict__ beta, const float* __restrict__ Wqkv,
    const float* __restrict__ Wout,
    ushort_t* __restrict__ xnh, ushort_t* __restrict__ xnl,
    ushort_t* __restrict__ wqh, ushort_t* __restrict__ wql,
    ushort_t* __restrict__ woh, ushort_t* __restrict__ wol) {
  __shared__ float Ts[64][68];
  int bidx = blockIdx.x;
  int tid = threadIdx.x;
  if (bidx < 256) {
    const float* src; ushort_t* dh; ushort_t* dl; int Nn, n0, k0;
    if (bidx < 192) {
      src = Wqkv; dh = wqh; dl = wql; Nn = 1536;
      n0 = (bidx % 24) * 64; k0 = (bidx / 24) * 64;
    } else {
      int l = bidx - 192;
      src = Wout; dh = woh; dl = wol; Nn = 512;
      n0 = (l % 8) * 64; k0 = (l / 8) * 64;
    }
#pragma unroll
    for (int it = 0; it < 4; ++it) {
      int idx = tid + it * 256;
      int r = idx >> 4, c4 = (idx & 15) * 4;
      *(float4*)&Ts[r][c4] = *(const float4*)&src[(size_t)(k0 + r) * Nn + n0 + c4];
    }
    __syncthreads();
#pragma unroll
    for (int it = 0; it < 2; ++it) {
      int idx = tid + it * 256;
      int n = idx >> 3, kc = (idx & 7) * 8;
      ushort_t hs[8], ls[8];
#pragma unroll
      for (int j = 0; j < 8; ++j) split2(Ts[kc + j][n], hs[j], ls[j]);
      uint4 uh, ul;
      uh.x = pack2(hs[0], hs[1]); uh.y = pack2(hs[2], hs[3]);
      uh.z = pack2(hs[4], hs[5]); uh.w = pack2(hs[6], hs[7]);
      ul.x = pack2(ls[0], ls[1]); ul.y = pack2(ls[2], ls[3]);
      ul.z = pack2(ls[4], ls[5]); ul.w = pack2(ls[6], ls[7]);
      size_t o = (size_t)(n0 + n) * 512 + k0 + kc;
      *(uint4*)&dh[o] = uh;
      *(uint4*)&dl[o] = ul;
    }
  } else {
    int row  = (bidx - 256) * 4 + (tid >> 6);
    int lane = tid & 63;
    const float4* xr = (const float4*)(x + (size_t)row * DIM_);
    float4 v0 = xr[lane * 2 + 0];
    float4 v1 = xr[lane * 2 + 1];
    float s  = v0.x + v0.y + v0.z + v0.w + v1.x + v1.y + v1.z + v1.w;
    float ss = v0.x*v0.x + v0.y*v0.y + v0.z*v0.z + v0.w*v0.w
             + v1.x*v1.x + v1.y*v1.y + v1.z*v1.z + v1.w*v1.w;
#pragma unroll
    for (int off = 32; off > 0; off >>= 1) {
      s  += __shfl_xor(s, off);
      ss += __shfl_xor(ss, off);
    }
    float mu  = s * (1.0f / DIM_);
    float var = ss * (1.0f / DIM_) - mu * mu;
    float rstd = rsqrtf(var + 1e-5f);
    float4 g0 = *(const float4*)&gamma[lane * 8];
    float4 g1 = *(const float4*)&gamma[lane * 8 + 4];
    float4 b0 = *(const float4*)&beta[lane * 8];
    float4 b1 = *(const float4*)&beta[lane * 8 + 4];
    float xv[8] = {v0.x, v0.y, v0.z, v0.w, v1.x, v1.y, v1.z, v1.w};
    float gv[8] = {g0.x, g0.y, g0.z, g0.w, g1.x, g1.y, g1.z, g1.w};
    float bv[8] = {b0.x, b0.y, b0.z, b0.w, b1.x, b1.y, b1.z, b1.w};
    ushort_t hs[8], ls[8];
#pragma unroll
    for (int j = 0; j < 8; ++j) {
      float xn = (xv[j] - mu) * rstd * gv[j] + bv[j];
      split2(xn, hs[j], ls[j]);
    }
    uint4 uh, ul;
    uh.x = pack2(hs[0], hs[1]); uh.y = pack2(hs[2], hs[3]);
    uh.z = pack2(hs[4], hs[5]); uh.w = pack2(hs[6], hs[7]);
    ul.x = pack2(ls[0], ls[1]); ul.y = pack2(ls[2], ls[3]);
    ul.z = pack2(ls[4], ls[5]); ul.w = pack2(ls[6], ls[7]);
    size_t o = (size_t)row * DIM_ + lane * 8;
    *(uint4*)&xnh[o] = uh;
    *(uint4*)&xnl[o] = ul;
  }
}

// ---------------------------------------------------------------------------
// Kernel C: qkv = xn @ Wqkv^T. REVERTED to the R1/R5-measured body (reg
// round-trip staging, 2 syncthreads/kt). R7's gload_lds conversion cost
// ~9-13 us total: its lever targets VALU-bound staging, not an
// already-vectorized reg round-trip (regime gate, rule #23).
// ---------------------------------------------------------------------------
__global__ __launch_bounds__(256) void qkv_gemm_mfma(
    const ushort_t* __restrict__ xnh, const ushort_t* __restrict__ xnl,
    const ushort_t* __restrict__ wth, const ushort_t* __restrict__ wtl,
    ushort_t* __restrict__ qh, ushort_t* __restrict__ ql,
    ushort_t* __restrict__ kho, ushort_t* __restrict__ klo,
    ushort_t* __restrict__ vt) {
  __shared__ ushort_t Ah[128 * 40], Al[128 * 40], Bh[128 * 40], Bl[128 * 40];
  int tid = threadIdx.x;
  int w = tid >> 6, lane = tid & 63, l31 = lane & 31, g = lane >> 5;
  int wm = w >> 1, wn = w & 1;
  int idx = blockIdx.x;
  int xcd = idx & 7, local = idx >> 3;
  int n0 = (local % 12) * 128;
  int m0 = ((local / 12) * 8 + xcd) * 128;

  f32x16 acc[2][2];
#pragma unroll
  for (int i = 0; i < 2; ++i)
#pragma unroll
    for (int j = 0; j < 2; ++j)
#pragma unroll
      for (int e = 0; e < 16; ++e) acc[i][j][e] = 0.0f;

  int fm[2], fc[2];
#pragma unroll
  for (int it = 0; it < 2; ++it) {
    int f = tid + it * 256;
    fm[it] = f >> 2;
    fc[it] = (f & 3) * 8;
  }

#pragma unroll 1
  for (int kt = 0; kt < 16; ++kt) {
    __syncthreads();
#pragma unroll
    for (int it = 0; it < 2; ++it) {
      size_t ao = (size_t)(m0 + fm[it]) * 512 + kt * 32 + fc[it];
      size_t bo = (size_t)(n0 + fm[it]) * 512 + kt * 32 + fc[it];
      uint4 tah = *(const uint4*)&xnh[ao];
      uint4 tal = *(const uint4*)&xnl[ao];
      uint4 tbh = *(const uint4*)&wth[bo];
      uint4 tbl = *(const uint4*)&wtl[bo];
      int o = fm[it] * 40 + fc[it];
      *(uint4*)&Ah[o] = tah;
      *(uint4*)&Al[o] = tal;
      *(uint4*)&Bh[o] = tbh;
      *(uint4*)&Bl[o] = tbl;
    }
    __syncthreads();
#pragma unroll
    for (int kc = 0; kc < 2; ++kc) {
      int off = kc * 16 + 8 * g;
      bf16x8 afh[2], afl[2], bfh[2], bfl[2];
#pragma unroll
      for (int rb = 0; rb < 2; ++rb) {
        int r = (wm * 64 + rb * 32 + l31) * 40 + off;
        afh[rb] = *(const bf16x8*)&Ah[r];
        afl[rb] = *(const bf16x8*)&Al[r];
      }
#pragma unroll
      for (int cb = 0; cb < 2; ++cb) {
        int r = (wn * 64 + cb * 32 + l31) * 40 + off;
        bfh[cb] = *(const bf16x8*)&Bh[r];
        bfl[cb] = *(const bf16x8*)&Bl[r];
      }
#pragma unroll
      for (int rb = 0; rb < 2; ++rb)
#pragma unroll
        for (int cb = 0; cb < 2; ++cb) {
          acc[rb][cb] = __builtin_amdgcn_mfma_f32_32x32x16_bf16(afh[rb], bfh[cb], acc[rb][cb], 0, 0, 0);
          acc[rb][cb] = __builtin_amdgcn_mfma_f32_32x32x16_bf16(afh[rb], bfl[cb], acc[rb][cb], 0, 0, 0);
          acc[rb][cb] = __builtin_amdgcn_mfma_f32_32x32x16_bf16(afl[rb], bfh[cb], acc[rb][cb], 0, 0, 0);
        }
    }
  }

  int part = n0 >> 9;
#pragma unroll
  for (int rb = 0; rb < 2; ++rb) {
    int m_base = m0 + wm * 64 + rb * 32;
#pragma unroll
    for (int cb = 0; cb < 2; ++cb) {
      int n_g = n0 + wn * 64 + cb * 32 + l31;
      int rem = n_g & 511, hh = rem >> 6, d = rem & 63;
      if (part == 2) {
#pragma unroll
        for (int grp = 0; grp < 4; ++grp) {
          int m_g = m_base + grp * 8 + 4 * g;
          int bb = m_g >> 11, tok = m_g & 2047;
          uint2 pk;
          pk.x = pack2(bf16_rn(acc[rb][cb][grp * 4 + 0]), bf16_rn(acc[rb][cb][grp * 4 + 1]));
          pk.y = pack2(bf16_rn(acc[rb][cb][grp * 4 + 2]), bf16_rn(acc[rb][cb][grp * 4 + 3]));
          *(uint2*)&vt[((size_t)(bb * 8 + hh) * 64 + d) * 2048 + tok] = pk;
        }
      } else {
        float sc = (part == 0) ? 0.125f : 1.0f;
        ushort_t* dsth = (part == 0) ? qh : kho;
        ushort_t* dstl = (part == 0) ? ql : klo;
#pragma unroll
        for (int reg = 0; reg < 16; ++reg) {
          int row = (reg & 3) + 8 * (reg >> 2) + 4 * g;
          int m_g = m_base + row;
          int bb = m_g >> 11, tok = m_g & 2047;
          ushort_t hi, lo;
          split2(acc[rb][cb][reg] * sc, hi, lo);
          size_t addr = ((size_t)(bb * 8 + hh) * 2048 + tok) * 64 + d;
          dsth[addr] = hi;
          dstl[addr] = lo;
        }
      }
    }
  }
}

// ---------------------------------------------------------------------------
// Kernel D: MFMA attention — byte-identical to R7's measured 76.5 us version
// (128 q / 4 waves, double-buffered K/V, m201 phase order, raw v_exp_f32,
// explicit vmcnt(0)+s_barrier per kt).
// ---------------------------------------------------------------------------
__global__ __launch_bounds__(256, 2) void attn_mfma(
    const ushort_t* __restrict__ qh, const ushort_t* __restrict__ ql,
    const ushort_t* __restrict__ kho, const ushort_t* __restrict__ klo,
    const ushort_t* __restrict__ vt, const float* __restrict__ R,
    const float* __restrict__ a, const float* __restrict__ c,
    ushort_t* __restrict__ aoh, ushort_t* __restrict__ aol) {
  __shared__ __align__(16) ushort_t KhS[2 * 4608];
  __shared__ __align__(16) ushort_t KlS[2 * 4608];
  __shared__ __align__(16) ushort_t VtS[2 * 4608];
  __shared__ float rsS[128];
  __shared__ float decl2S[16];

  int tid = threadIdx.x;
  int w = tid >> 6, lane = tid & 63, l31 = lane & 31, g = lane >> 5;
  int bh = blockIdx.x;
  int qt = blockIdx.y;               // 128-query tile == timepoint index
  int b = bh >> 3, h = bh & 7;

  // Q fragments: wave w owns rows qt*128 + w*32 .. +32 (q = l31 -> B operand col)
  int qrow = qt * 128 + w * 32 + l31;
  size_t qoff = ((size_t)bh * 2048 + qrow) * 64;
  bf16x8 qfh[4], qfl[4];
#pragma unroll
  for (int d0i = 0; d0i < 4; ++d0i) {
    qfh[d0i] = *(const bf16x8*)&qh[qoff + d0i * 16 + 8 * g];
    qfl[d0i] = *(const bf16x8*)&ql[qoff + d0i * 16 + 8 * g];
  }

  const ushort_t* kbase = kho + (size_t)bh * 2048 * 64;
  const ushort_t* lbase = klo + (size_t)bh * 2048 * 64;
  const ushort_t* vbase = vt + (size_t)bh * 64 * 2048;

  // decay table: 16 kt-pairs, log2e folded in
  if (tid < 16) {
    float aab = fabsf(a[h]);
    float cab = fabsf(c[h]);
    float Rv = R[b * (T_ * T_) + qt * T_ + tid];
    decl2S[tid] = 1.4426950408889634f / (1.0f + __expf(aab * Rv - cab));
  }

  // padded-stride staging map: per chunk, per lane -> (row r, slot-offset j8)
  int r_[3], j8_[3];
#pragma unroll
  for (int i = 0; i < 3; ++i) {
    int ch = (i < 2) ? (w + i * 4) : 8;
    int u = ch * 512 + lane * 8;          // ushort index in padded array
    int r = u / 72;                        // 0..63
    int j = (u - r * 72) >> 3;             // 0..8 (8 = pad slot)
    r_[i] = r;
    j8_[i] = (j == 8) ? 0 : (j << 3);      // pad: duplicate row-start fetch
  }
  int a8 = (w < 3) ? w : 0;                // which array this wave's chunk-8 is

  f32x16 oacc[2];
#pragma unroll
  for (int t = 0; t < 2; ++t)
#pragma unroll
    for (int i = 0; i < 16; ++i) oacc[t][i] = 0.0f;
  float rsp[4] = {0.0f, 0.0f, 0.0f, 0.0f};

  // prologue: stage kt=0 into buf 0 (7 gloads); __syncthreads drains fully
  {
#pragma unroll
    for (int i = 0; i < 2; ++i) {
      int cb = (w + i * 4) * 512;
      gload_lds16(&kbase[(size_t)r_[i] * 64 + j8_[i]], &KhS[cb]);
      gload_lds16(&lbase[(size_t)r_[i] * 64 + j8_[i]], &KlS[cb]);
      gload_lds16(&vbase[(size_t)r_[i] * 2048 + j8_[i]], &VtS[cb]);
    }
    int cb8 = 8 * 512;
    if (a8 == 0)      gload_lds16(&kbase[(size_t)r_[2] * 64 + j8_[2]], &KhS[cb8]);
    else if (a8 == 1) gload_lds16(&lbase[(size_t)r_[2] * 64 + j8_[2]], &KlS[cb8]);
    else              gload_lds16(&vbase[(size_t)r_[2] * 2048 + j8_[2]], &VtS[cb8]);
  }
  __syncthreads();

  int cur = 0;

#pragma unroll 1
  for (int kt = 0; kt < 32; ++kt) {
    int kb = cur * 4608;

    // --- Phase 1: ds_read ALL fragments of buf[cur] into registers.
    float decl2 = decl2S[kt >> 1];
    bf16x8 kfh[2][4], kfl[2][4], vf[2][4];
#pragma unroll
    for (int khalf = 0; khalf < 2; ++khalf) {
      int krow = kb + (khalf * 32 + l31) * 72;
#pragma unroll
      for (int d0i = 0; d0i < 4; ++d0i) {
        int off = krow + d0i * 16 + 8 * g;
        kfh[khalf][d0i] = *(const bf16x8*)&KhS[off];
        kfl[khalf][d0i] = *(const bf16x8*)&KlS[off];
      }
    }
#pragma unroll
    for (int dt = 0; dt < 2; ++dt) {
      int vrow = kb + (dt * 32 + l31) * 72;
#pragma unroll
      for (int kc = 0; kc < 4; ++kc)
        vf[dt][kc] = *(const bf16x8*)&VtS[vrow + kc * 16 + 8 * g];
    }
    __builtin_amdgcn_sched_barrier(0);

    // --- Phase 2: stage kt+1 into buf cur^1 (no LDS read follows this)
    if (kt + 1 < 32) {
      int lb = (cur ^ 1) * 4608;
      int kk = kt + 1;
#pragma unroll
      for (int i = 0; i < 2; ++i) {
        int cb = lb + (w + i * 4) * 512;
        gload_lds16(&kbase[(size_t)kk * 4096 + r_[i] * 64 + j8_[i]], &KhS[cb]);
        gload_lds16(&lbase[(size_t)kk * 4096 + r_[i] * 64 + j8_[i]], &KlS[cb]);
        gload_lds16(&vbase[(size_t)r_[i] * 2048 + kk * 64 + j8_[i]], &VtS[cb]);
      }
      int cb8 = lb + 8 * 512;
      if (a8 == 0)      gload_lds16(&kbase[(size_t)kk * 4096 + r_[2] * 64 + j8_[2]], &KhS[cb8]);
      else if (a8 == 1) gload_lds16(&lbase[(size_t)kk * 4096 + r_[2] * 64 + j8_[2]], &KlS[cb8]);
      else              gload_lds16(&vbase[(size_t)r_[2] * 2048 + kk * 64 + j8_[2]], &VtS[cb8]);
    }
    __builtin_amdgcn_sched_barrier(0);

    // --- Phase 3: register-only compute.
    // S^T = mfma(K, Q): out col = l31 = q, row = crow(reg,g) = key.
    bf16x8 pa[4];
#pragma unroll
    for (int khalf = 0; khalf < 2; ++khalf) {
      f32x16 sacc;
#pragma unroll
      for (int i = 0; i < 16; ++i) sacc[i] = 0.0f;
#pragma unroll
      for (int d0i = 0; d0i < 4; ++d0i) {
        sacc = __builtin_amdgcn_mfma_f32_32x32x16_bf16(kfh[khalf][d0i], qfh[d0i], sacc, 0, 0, 0);
        sacc = __builtin_amdgcn_mfma_f32_32x32x16_bf16(kfl[khalf][d0i], qfh[d0i], sacc, 0, 0, 0);
        sacc = __builtin_amdgcn_mfma_f32_32x32x16_bf16(kfh[khalf][d0i], qfl[d0i], sacc, 0, 0, 0);
      }
#pragma unroll
      for (int reg = 0; reg < 16; ++reg) {
        float pvv = exp2_raw(fmaxf(sacc[reg], 0.0f) * decl2);
        rsp[reg & 3] += pvv;
        sacc[reg] = pvv;
      }
      // cvt_pk pairs -> dwords; permlane32_swap yields A-fragment words.
#pragma unroll
      for (int hf = 0; hf < 2; ++hf) {
        unsigned d0 = cvt_pk_bf16(sacc[hf * 8 + 0], sacc[hf * 8 + 1]);
        unsigned d1 = cvt_pk_bf16(sacc[hf * 8 + 2], sacc[hf * 8 + 3]);
        unsigned d2 = cvt_pk_bf16(sacc[hf * 8 + 4], sacc[hf * 8 + 5]);
        unsigned d3 = cvt_pk_bf16(sacc[hf * 8 + 6], sacc[hf * 8 + 7]);
        permlane32_swap(d0, d2);
        permlane32_swap(d1, d3);
        uint4 u; u.x = d0; u.y = d1; u.z = d2; u.w = d3;
        pa[khalf * 2 + hf] = __builtin_bit_cast(bf16x8, u);
      }
    }

    // O += P V  (P and V fully in registers)
#pragma unroll
    for (int dt = 0; dt < 2; ++dt)
#pragma unroll
      for (int kc = 0; kc < 4; ++kc)
        oacc[dt] = __builtin_amdgcn_mfma_f32_32x32x16_bf16(pa[kc], vf[dt][kc], oacc[dt], 0, 0, 0);

    // own loads were issued a full compute-phase ago -> wait ~free; after the
    // barrier ALL waves' loads have landed => next iteration's reads safe.
    asm volatile("s_waitcnt vmcnt(0)" ::: "memory");
    __builtin_amdgcn_s_barrier();
    cur ^= 1;
  }

  // row sums: combine partials, then across g halves, then LDS redistribute.
  float rs = (rsp[0] + rsp[1]) + (rsp[2] + rsp[3]);
  rs += __shfl_xor(rs, 32);
  rsS[w * 32 + l31] = rs;            // both g halves write identical value

  // normalize + write aout hi/lo [b][tok][h*64+d]
#pragma unroll
  for (int reg = 0; reg < 16; ++reg) {
    int row = (reg & 3) + 8 * (reg >> 2) + 4 * g;
    float invs = 1.0f / rsS[w * 32 + row];
    int tok = qt * 128 + w * 32 + row;
#pragma unroll
    for (int dt = 0; dt < 2; ++dt) {
      int d = dt * 32 + l31;
      ushort_t hi, lo;
      split2(oacc[dt][reg] * invs, hi, lo);
      size_t addr = ((size_t)b * 2048 + tok) * 512 + h * 64 + d;
      aoh[addr] = hi;
      aol[addr] = lo;
    }
  }
}

// ---------------------------------------------------------------------------
// Kernel E: out = aout @ Wout^T. REVERTED to the R1/R5-measured body.
// ---------------------------------------------------------------------------
__global__ __launch_bounds__(256) void out_gemm_mfma(
    const ushort_t* __restrict__ ah, const ushort_t* __restrict__ al,
    const ushort_t* __restrict__ wth, const ushort_t* __restrict__ wtl,
    float* __restrict__ out) {
  __shared__ ushort_t Ah[128 * 40], Al[128 * 40], Bh[128 * 40], Bl[128 * 40];
  int tid = threadIdx.x;
  int w = tid >> 6, lane = tid & 63, l31 = lane & 31, g = lane >> 5;
  int wm = w >> 1, wn = w & 1;
  int idx = blockIdx.x;
  int xcd = idx & 7, local = idx >> 3;
  int n0 = (local & 3) * 128;
  int m0 = ((local >> 2) * 8 + xcd) * 128;

  f32x16 acc[2][2];
#pragma unroll
  for (int i = 0; i < 2; ++i)
#pragma unroll
    for (int j = 0; j < 2; ++j)
#pragma unroll
      for (int e = 0; e < 16; ++e) acc[i][j][e] = 0.0f;

  int fm[2], fc[2];
#pragma unroll
  for (int it = 0; it < 2; ++it) {
    int f = tid + it * 256;
    fm[it] = f >> 2;
    fc[it] = (f & 3) * 8;
  }

#pragma unroll 1
  for (int kt = 0; kt < 16; ++kt) {
    __syncthreads();
#pragma unroll
    for (int it = 0; it < 2; ++it) {
      size_t ao = (size_t)(m0 + fm[it]) * 512 + kt * 32 + fc[it];
      size_t bo = (size_t)(n0 + fm[it]) * 512 + kt * 32 + fc[it];
      uint4 tah = *(const uint4*)&ah[ao];
      uint4 tal = *(const uint4*)&al[ao];
      uint4 tbh = *(const uint4*)&wth[bo];
      uint4 tbl = *(const uint4*)&wtl[bo];
      int o = fm[it] * 40 + fc[it];
      *(uint4*)&Ah[o] = tah;
      *(uint4*)&Al[o] = tal;
      *(uint4*)&Bh[o] = tbh;
      *(uint4*)&Bl[o] = tbl;
    }
    __syncthreads();
#pragma unroll
    for (int kc = 0; kc < 2; ++kc) {
      int off = kc * 16 + 8 * g;
      bf16x8 afh[2], afl[2], bfh[2], bfl[2];
#pragma unroll
      for (int rb = 0; rb < 2; ++rb) {
        int r = (wm * 64 + rb * 32 + l31) * 40 + off;
        afh[rb] = *(const bf16x8*)&Ah[r];
        afl[rb] = *(const bf16x8*)&Al[r];
      }
#pragma unroll
      for (int cb = 0; cb < 2; ++cb) {
        int r = (wn * 64 + cb * 32 + l31) * 40 + off;
        bfh[cb] = *(const bf16x8*)&Bh[r];
        bfl[cb] = *(const bf16x8*)&Bl[r];
      }
#pragma unroll
      for (int rb = 0; rb < 2; ++rb)
#pragma unroll
        for (int cb = 0; cb < 2; ++cb) {
          acc[rb][cb] = __builtin_amdgcn_mfma_f32_32x32x16_bf16(afh[rb], bfh[cb], acc[rb][cb], 0, 0, 0);
          acc[rb][cb] = __builtin_amdgcn_mfma_f32_32x32x16_bf16(afh[rb], bfl[cb], acc[rb][cb], 0, 0, 0);
          acc[rb][cb] = __builtin_amdgcn_mfma_f32_32x32x16_bf16(afl[rb], bfh[cb], acc[rb][cb], 0, 0, 0);
        }
    }
  }

#pragma unroll
  for (int rb = 0; rb < 2; ++rb) {
    int m_base = m0 + wm * 64 + rb * 32;
#pragma unroll
    for (int cb = 0; cb < 2; ++cb) {
      int n_g = n0 + wn * 64 + cb * 32 + l31;
#pragma unroll
      for (int reg = 0; reg < 16; ++reg) {
        int row = (reg & 3) + 8 * (reg >> 2) + 4 * g;
        out[(size_t)(m_base + row) * 512 + n_g] = acc[rb][cb][reg];
      }
    }
  }
}

// ---------------------------------------------------------------------------
extern "C" void kernel_launch(void* const* d_in, const int* in_sizes, int n_in,
                              void* d_out, int out_size, void* d_ws, size_t ws_size,
                              hipStream_t stream) {
  (void)in_sizes; (void)n_in;
  const float* x     = (const float*)d_in[0];
  const float* R     = (const float*)d_in[1];
  const float* gamma = (const float*)d_in[2];
  const float* beta  = (const float*)d_in[3];
  const float* Wqkv  = (const float*)d_in[4];
  const float* Wout  = (const float*)d_in[5];
  const float* av    = (const float*)d_in[6];
  const float* cv    = (const float*)d_in[7];
  float* out = (float*)d_out;

  const size_t EL  = (size_t)B_ * N_ * DIM_;     // 4,194,304 elements
  const size_t SZT = EL * sizeof(ushort_t);      // 8 MiB per bf16 tensor

  char* p = (char*)d_ws;
  ushort_t* wqh = (ushort_t*)p;                  p += (size_t)1536 * 512 * 2;
  ushort_t* wql = (ushort_t*)p;                  p += (size_t)1536 * 512 * 2;
  ushort_t* woh = (ushort_t*)p;                  p += (size_t)512 * 512 * 2;
  ushort_t* wol = (ushort_t*)p;                  p += (size_t)512 * 512 * 2;
  ushort_t* qhb = (ushort_t*)p;                  p += SZT;
  ushort_t* qlb = (ushort_t*)p;                  p += SZT;
  ushort_t* khb = (ushort_t*)p;                  p += SZT;
  ushort_t* klb = (ushort_t*)p;                  p += SZT;
  ushort_t* vtb = (ushort_t*)p;                  p += SZT;
  size_t base_need = (size_t)(p - (char*)d_ws);
  size_t needA = base_need + 2 * SZT;

  bool planA = (ws_size >= needA);
  ushort_t* xnh = planA ? (ushort_t*)p : (ushort_t*)d_out;
  ushort_t* xnl = xnh + EL;
  float* gemm_dst = planA ? out : (float*)qhb;

  prep_kernel<<<dim3(2304), dim3(256), 0, stream>>>(x, gamma, beta, Wqkv, Wout,
                                                    xnh, xnl, wqh, wql, woh, wol);
  qkv_gemm_mfma<<<dim3(768), dim3(256), 0, stream>>>(xnh, xnl, wqh, wql,
                                                     qhb, qlb, khb, klb, vtb);
  attn_mfma<<<dim3(32, 16), dim3(256), 0, stream>>>(qhb, qlb, khb, klb, vtb,
                                                    R, av, cv, xnh, xnl);
  out_gemm_mfma<<<dim3(256), dim3(256), 0, stream>>>(xnh, xnl, woh, wol, gemm_dst);
  if (!planA) {
    hipMemcpyAsync(out, gemm_dst, (size_t)out_size * sizeof(float),
                   hipMemcpyDeviceToDevice, stream);
  }
}